// Round 1
// baseline (388.430 us; speedup 1.0000x reference)
//
#include <hip/hip_runtime.h>
#include <hip/hip_bf16.h>

#define B_ 2
#define T_ 2048
#define E_ 1024
#define H_ 16
#define D_ 64
#define F_ 3072
#define M_ 4096  // B_*T_

typedef __attribute__((ext_vector_type(8))) short short8v;
typedef __attribute__((ext_vector_type(4))) short short4v;
typedef __attribute__((ext_vector_type(4))) float float4v;

__device__ __forceinline__ ushort f2bf(float f) {
    union { float f; unsigned u; } v; v.f = f;
    unsigned u = v.u;
    unsigned r = (u + 0x7FFFu + ((u >> 16) & 1u)) >> 16;
    return (ushort)r;
}

// ---- fp32 -> bf16 conversion, 4 elems per thread ----
__global__ void cvt_kernel(const float* __restrict__ in, ushort* __restrict__ out, int n4) {
    int i = blockIdx.x * blockDim.x + threadIdx.x;
    if (i >= n4) return;
    float4 v = ((const float4*)in)[i];
    ushort4 o;
    o.x = f2bf(v.x); o.y = f2bf(v.y); o.z = f2bf(v.z); o.w = f2bf(v.w);
    ((ushort4*)out)[i] = o;
}

// ---- GEMM: C[M][N] = A[M][K] * Bt[N][K]^T  (both bf16, K multiple of 32) ----
// MODE 0: qkv epilogue (bias, q-scale, scatter to [3][B][H][T][D] bf16)
// MODE 1: fp32 out epilogue (bias)
template <int MODE>
__global__ __launch_bounds__(256) void gemm_bt(const ushort* __restrict__ A,
                                               const ushort* __restrict__ Bt,
                                               const float* __restrict__ bias,
                                               void* __restrict__ Cout,
                                               int Ndim, int K) {
    int lane = threadIdx.x & 63;
    int w = threadIdx.x >> 6;
    int wr = w >> 1, wc = w & 1;
    int mb = blockIdx.x * 128 + wr * 64;
    int nb = blockIdx.y * 128 + wc * 64;
    int r15 = lane & 15, g = lane >> 4;

    const ushort* Abase = A + (size_t)(mb + r15) * K + g * 8;
    const ushort* Bbase = Bt + (size_t)(nb + r15) * K + g * 8;

    float4v acc[4][4] = {};
    for (int k0 = 0; k0 < K; k0 += 32) {
        short8v af[4], bf[4];
#pragma unroll
        for (int r = 0; r < 4; ++r)
            af[r] = *(const short8v*)(Abase + (size_t)r * 16 * K + k0);
#pragma unroll
        for (int c = 0; c < 4; ++c)
            bf[c] = *(const short8v*)(Bbase + (size_t)c * 16 * K + k0);
#pragma unroll
        for (int r = 0; r < 4; ++r)
#pragma unroll
            for (int c = 0; c < 4; ++c)
                acc[r][c] = __builtin_amdgcn_mfma_f32_16x16x32_bf16(af[r], bf[c], acc[r][c], 0, 0, 0);
    }

    if (MODE == 0) {
        ushort* qkv = (ushort*)Cout;
#pragma unroll
        for (int r = 0; r < 4; ++r)
#pragma unroll
            for (int c = 0; c < 4; ++c)
#pragma unroll
                for (int ri = 0; ri < 4; ++ri) {
                    int m = mb + r * 16 + g * 4 + ri;
                    int n = nb + c * 16 + r15;
                    float v = acc[r][c][ri] + bias[n];
                    int which = n >> 10;          // 0:q 1:k 2:v
                    int e = n & 1023;
                    if (which == 0) v *= 0.125f;  // D^-0.5
                    int h = e >> 6, d = e & 63;
                    int b = m >> 11, t = m & 2047;
                    qkv[(size_t)which * ((size_t)M_ * E_) +
                        ((size_t)(b * H_ + h) * T_ + t) * D_ + d] = f2bf(v);
                }
    } else {
        float* out = (float*)Cout;
#pragma unroll
        for (int r = 0; r < 4; ++r)
#pragma unroll
            for (int c = 0; c < 4; ++c)
#pragma unroll
                for (int ri = 0; ri < 4; ++ri) {
                    int m = mb + r * 16 + g * 4 + ri;
                    int n = nb + c * 16 + r15;
                    out[(size_t)m * Ndim + n] = acc[r][c][ri] + bias[n];
                }
    }
}

// ---- flash attention: 1 block = (head, 64 q-rows); wave = 16 q-rows ----
// S^T = mfma(K_frag, Q_frag): C-layout == A-layout of P for the PV mfma.
__global__ __launch_bounds__(256) void attn_kernel(const ushort* __restrict__ qkv,
                                                   ushort* __restrict__ Ob) {
    int lane = threadIdx.x & 63;
    int w = threadIdx.x >> 6;
    int bh = blockIdx.x >> 5;   // b*H + h
    int qt = blockIdx.x & 31;
    int r15 = lane & 15, g = lane >> 4;
    int qb = qt * 64 + w * 16;

    const ushort* Qh = qkv + (size_t)bh * T_ * D_;
    const ushort* Kh = qkv + (size_t)M_ * E_ + (size_t)bh * T_ * D_;
    const ushort* Vh = qkv + (size_t)2 * M_ * E_ + (size_t)bh * T_ * D_;

    short8v qf[2];
#pragma unroll
    for (int kk = 0; kk < 2; ++kk)
        qf[kk] = *(const short8v*)(Qh + (size_t)(qb + r15) * D_ + kk * 32 + g * 8);

    float4v oacc[4] = {};
    float m_run = -1e30f, l_run = 0.f;

    for (int kt = 0; kt < T_ / 16; ++kt) {
        const ushort* Krow = Kh + (size_t)(kt * 16 + r15) * D_ + g * 8;
        short8v kf0 = *(const short8v*)(Krow);
        short8v kf1 = *(const short8v*)(Krow + 32);
        float4v st = {0.f, 0.f, 0.f, 0.f};
        st = __builtin_amdgcn_mfma_f32_16x16x32_bf16(kf0, qf[0], st, 0, 0, 0);
        st = __builtin_amdgcn_mfma_f32_16x16x32_bf16(kf1, qf[1], st, 0, 0, 0);
        // lane holds S^T[key=kt*16+g*4+ri][q=r15]

        float tmax = fmaxf(fmaxf(st[0], st[1]), fmaxf(st[2], st[3]));
        tmax = fmaxf(tmax, __shfl_xor(tmax, 16));
        tmax = fmaxf(tmax, __shfl_xor(tmax, 32));
        float mnew = fmaxf(m_run, tmax);
        float corr = __expf(m_run - mnew);
        float p0 = __expf(st[0] - mnew), p1 = __expf(st[1] - mnew);
        float p2 = __expf(st[2] - mnew), p3 = __expf(st[3] - mnew);
        float ts = p0 + p1 + p2 + p3;
        ts += __shfl_xor(ts, 16);
        ts += __shfl_xor(ts, 32);
        l_run = l_run * corr + ts;
        m_run = mnew;

        // rescale factors for O rows q' = g*4+ri (stats live at lane q')
        float c0 = __shfl(corr, g * 4 + 0);
        float c1 = __shfl(corr, g * 4 + 1);
        float c2 = __shfl(corr, g * 4 + 2);
        float c3 = __shfl(corr, g * 4 + 3);

        int krow = kt * 16 + g * 4;
        const ushort* vp0 = Vh + (size_t)krow * D_ + r15;
#if __has_builtin(__builtin_amdgcn_mfma_f32_16x16x16bf16_1k)
        short4v pf;
        pf[0] = (short)f2bf(p0); pf[1] = (short)f2bf(p1);
        pf[2] = (short)f2bf(p2); pf[3] = (short)f2bf(p3);
#pragma unroll
        for (int c = 0; c < 4; ++c) {
            const ushort* vp = vp0 + c * 16;
            short4v vf;
            vf[0] = (short)vp[0];
            vf[1] = (short)vp[64];
            vf[2] = (short)vp[128];
            vf[3] = (short)vp[192];
            oacc[c][0] *= c0; oacc[c][1] *= c1; oacc[c][2] *= c2; oacc[c][3] *= c3;
            oacc[c] = __builtin_amdgcn_mfma_f32_16x16x16bf16_1k(pf, vf, oacc[c], 0, 0, 0);
        }
#else
        // zero-padded 16x16x32 fallback (same permuted k-ordering on A and B)
        short8v pf8 = {};
        pf8[0] = (short)f2bf(p0); pf8[1] = (short)f2bf(p1);
        pf8[2] = (short)f2bf(p2); pf8[3] = (short)f2bf(p3);
#pragma unroll
        for (int c = 0; c < 4; ++c) {
            const ushort* vp = vp0 + c * 16;
            short8v vf8 = {};
            vf8[0] = (short)vp[0];
            vf8[1] = (short)vp[64];
            vf8[2] = (short)vp[128];
            vf8[3] = (short)vp[192];
            oacc[c][0] *= c0; oacc[c][1] *= c1; oacc[c][2] *= c2; oacc[c][3] *= c3;
            oacc[c] = __builtin_amdgcn_mfma_f32_16x16x32_bf16(pf8, vf8, oacc[c], 0, 0, 0);
        }
#endif
    }

    float s0 = __shfl(l_run, g * 4 + 0);
    float s1 = __shfl(l_run, g * 4 + 1);
    float s2 = __shfl(l_run, g * 4 + 2);
    float s3 = __shfl(l_run, g * 4 + 3);
    float i0 = 1.f / s0, i1 = 1.f / s1, i2 = 1.f / s2, i3 = 1.f / s3;

    int b = bh >> 4, h = bh & 15;
#pragma unroll
    for (int c = 0; c < 4; ++c) {
        size_t base = ((size_t)b * T_ + qb + g * 4) * E_ + h * 64 + c * 16 + r15;
        Ob[base]          = f2bf(oacc[c][0] * i0);
        Ob[base + E_]     = f2bf(oacc[c][1] * i1);
        Ob[base + 2 * E_] = f2bf(oacc[c][2] * i2);
        Ob[base + 3 * E_] = f2bf(oacc[c][3] * i3);
    }
}

extern "C" void kernel_launch(void* const* d_in, const int* in_sizes, int n_in,
                              void* d_out, int out_size, void* d_ws, size_t ws_size,
                              hipStream_t stream) {
    const float* query = (const float*)d_in[0];
    const float* Wqkv  = (const float*)d_in[1];
    const float* bqkv  = (const float*)d_in[2];
    const float* Wo    = (const float*)d_in[3];
    const float* bo    = (const float*)d_in[4];
    float* out = (float*)d_out;

    // workspace layout (bf16 elements): total 24M elems = 48 MB
    ushort* Xb    = (ushort*)d_ws;                       // M_*E_   (8 MB)
    ushort* Wqkvb = Xb + (size_t)M_ * E_;                // F_*E_   (6 MB)
    ushort* Wob   = Wqkvb + (size_t)F_ * E_;             // E_*E_   (2 MB)
    ushort* QKVb  = Wob + (size_t)E_ * E_;               // 3*M_*E_ (24 MB), [3][B][H][T][D]
    ushort* Ob    = QKVb + (size_t)3 * M_ * E_;          // M_*E_   (8 MB), [B*T][E]

    cvt_kernel<<<(M_ * E_ / 4 + 255) / 256, 256, 0, stream>>>(query, Xb, M_ * E_ / 4);
    cvt_kernel<<<(F_ * E_ / 4 + 255) / 256, 256, 0, stream>>>(Wqkv, Wqkvb, F_ * E_ / 4);
    cvt_kernel<<<(E_ * E_ / 4 + 255) / 256, 256, 0, stream>>>(Wo, Wob, E_ * E_ / 4);

    gemm_bt<0><<<dim3(M_ / 128, F_ / 128), 256, 0, stream>>>(Xb, Wqkvb, bqkv, QKVb, F_, E_);
    attn_kernel<<<(B_ * H_) * (T_ / 64), 256, 0, stream>>>(QKVb, Ob);
    gemm_bt<1><<<dim3(M_ / 128, E_ / 128), 256, 0, stream>>>(Ob, Wob, bo, out, E_, E_);
}